// Round 6
// baseline (221.395 us; speedup 1.0000x reference)
//
#include <hip/hip_runtime.h>

#define D 64
#define NG 64

typedef float f32x16 __attribute__((ext_vector_type(16)));

// ---------- pass 1: fused x@{Wq,Wk,Wv,Ws} + bias ----------
// Wave w of each block computes matrix w. Lane l holds W-column l in 64 VGPRs.
// The (wave-uniform) x row is broadcast through SGPRs via s_load_dwordx16, so
// the inner loop is pure v_fma_f32 with an SGPR multiplier — no LDS, no shfl.
__global__ __launch_bounds__(256) void k_linear4(
    const float* __restrict__ x,
    const float* __restrict__ Wq, const float* __restrict__ bq,
    const float* __restrict__ Wk, const float* __restrict__ bk,
    const float* __restrict__ Wv, const float* __restrict__ bv,
    const float* __restrict__ Ws, const float* __restrict__ bs,
    float* __restrict__ q, float* __restrict__ k, float* __restrict__ v,
    float* __restrict__ sp, int N)
{
  const int lane = threadIdx.x & 63;
  const int w    = threadIdx.x >> 6;   // wave id = matrix id

  const float* Wm = (w==0) ? Wq : (w==1) ? Wk : (w==2) ? Wv : Ws;
  const float* bm = (w==0) ? bq : (w==1) ? bk : (w==2) ? bv : bs;
  float*       dm = (w==0) ? q  : (w==1) ? k  : (w==2) ? v  : sp;

  float wr[D];
  #pragma unroll
  for (int j = 0; j < D; ++j) wr[j] = Wm[j*D + lane];
  const float bias = bm[lane];

  for (int row = blockIdx.x; row < N; row += gridDim.x){
    const float* xrow = x + (size_t)row * D;
    f32x16 x0, x1, x2, x3;
    asm volatile("s_load_dwordx16 %0, %1, 0x0"  : "=s"(x0) : "s"(xrow));
    asm volatile("s_load_dwordx16 %0, %1, 0x40" : "=s"(x1) : "s"(xrow));
    asm volatile("s_load_dwordx16 %0, %1, 0x80" : "=s"(x2) : "s"(xrow));
    asm volatile("s_load_dwordx16 %0, %1, 0xc0" : "=s"(x3) : "s"(xrow));
    asm volatile("s_waitcnt lgkmcnt(0)"
                 : "+s"(x0), "+s"(x1), "+s"(x2), "+s"(x3));
    float acc = bias;
    #pragma unroll
    for (int j = 0; j < 16; ++j) acc = fmaf(x0[j], wr[j],      acc);
    #pragma unroll
    for (int j = 0; j < 16; ++j) acc = fmaf(x1[j], wr[16 + j], acc);
    #pragma unroll
    for (int j = 0; j < 16; ++j) acc = fmaf(x2[j], wr[32 + j], acc);
    #pragma unroll
    for (int j = 0; j < 16; ++j) acc = fmaf(x3[j], wr[48 + j], acc);
    dm[(size_t)row * D + lane] = acc;
  }
}

// ---------- CSR build (group edges by dst) ----------
__global__ __launch_bounds__(256) void k_hist(
    const int* __restrict__ edst, int* __restrict__ deg, int E)
{
  int e = blockIdx.x*256 + threadIdx.x;
  if (e < E) atomicAdd(deg + edst[e], 1);
}

__global__ __launch_bounds__(256) void k_scan1(
    const int* __restrict__ deg, int* __restrict__ ptr, int* __restrict__ bsum, int N)
{
  __shared__ int s[256];
  int t = threadIdx.x;
  int i = blockIdx.x*256 + t;
  int val = (i < N) ? deg[i] : 0;
  s[t] = val; __syncthreads();
  #pragma unroll
  for (int off=1; off<256; off<<=1){
    int tmp = (t>=off) ? s[t-off] : 0;
    __syncthreads();
    s[t] += tmp;
    __syncthreads();
  }
  if (i < N) ptr[i] = s[t] - val;          // exclusive
  if (t == 255) bsum[blockIdx.x] = s[255]; // block total
}

__global__ __launch_bounds__(256) void k_scan2(
    const int* __restrict__ bsum, int* __restrict__ boff, int NB)
{
  __shared__ int s[256];
  int t = threadIdx.x;
  int val = (t < NB) ? bsum[t] : 0;
  s[t] = val; __syncthreads();
  #pragma unroll
  for (int off=1; off<256; off<<=1){
    int tmp = (t>=off) ? s[t-off] : 0;
    __syncthreads();
    s[t] += tmp;
    __syncthreads();
  }
  if (t < NB) boff[t] = s[t] - val;
}

__global__ __launch_bounds__(256) void k_scan3(
    int* __restrict__ ptr, const int* __restrict__ boff,
    int* __restrict__ cursor, int N)
{
  int i = blockIdx.x*256 + threadIdx.x;
  if (i < N){
    int p = ptr[i] + boff[blockIdx.x];
    ptr[i] = p;
    cursor[i] = p;
  }
}

__global__ __launch_bounds__(256) void k_fill(
    const int* __restrict__ esrc, const int* __restrict__ edst,
    int* __restrict__ cursor, int* __restrict__ csr_src, int E)
{
  int e = blockIdx.x*256 + threadIdx.x;
  if (e >= E) return;
  int pos = atomicAdd(cursor + edst[e], 1);
  csr_src[pos] = esrc[e];
}

// ---------- fused attention gather: logits + softmax + PV + skip + ReLU ----------
// Softmax WITHOUT max-subtraction: logits ~ N(0,1) (q,k rows are ~unit normal,
// scaled by 1/sqrt(D)); max over 800K edges ~ 6, exp(6)=403 — no overflow.
// Hard guard: clamp logit at 60 (exp(60)~1e26, 12 decades below f32 max).
// Mathematically identical alpha; removes the online-rescale branch and the
// expensive libm expf (uses v_exp_f32 via __expf).
__global__ __launch_bounds__(256) void k_attend(
    const float* __restrict__ q, const float* __restrict__ k,
    const float* __restrict__ v, float* __restrict__ sp,
    const int* __restrict__ ptr, const int* __restrict__ deg,
    const int* __restrict__ csr_src, int N)
{
  int node = blockIdx.x*4 + (threadIdx.x >> 6);
  if (node >= N) return;
  const int lane = threadIdx.x & 63;
  const int grp  = lane >> 4;
  const int gl   = lane & 15;

  float4 q4 = ((const float4*)(q + (size_t)node*D))[gl];
  int p0 = ptr[node], dg = deg[node];

  float den = 0.f;
  float ax=0.f, ay=0.f, az=0.f, aw=0.f;

  for (int base = 0; base < dg; base += 64){
    int nb = min(64, dg - base);
    int sidx = (lane < nb) ? csr_src[p0 + base + lane] : 0;
    int T = (nb + 3) >> 2;               // uniform trip count for all groups
    #pragma unroll 2
    for (int t = 0; t < T; ++t){
      int ei  = grp + 4*t;
      int eis = min(ei, nb - 1);         // clamped: always a valid source lane
      int s = __shfl(sidx, eis, 64);     // executed by all 64 lanes
      if (ei < nb){                      // group-uniform predicate
        float4 k4 = ((const float4*)(k + (size_t)s*D))[gl];
        float p = q4.x*k4.x + q4.y*k4.y + q4.z*k4.z + q4.w*k4.w;
        p += __shfl_xor(p, 1, 64);
        p += __shfl_xor(p, 2, 64);
        p += __shfl_xor(p, 4, 64);
        p += __shfl_xor(p, 8, 64);
        float ex = __expf(fminf(p * 0.125f, 60.f));   // 1/sqrt(64)
        float4 v4 = ((const float4*)(v + (size_t)s*D))[gl];
        den += ex;
        ax = fmaf(ex, v4.x, ax);
        ay = fmaf(ex, v4.y, ay);
        az = fmaf(ex, v4.z, az);
        aw = fmaf(ex, v4.w, aw);
      }
    }
  }

  // merge the 4 groups (lanes gl, gl+16, gl+32, gl+48): plain sums
  #pragma unroll
  for (int off = 16; off <= 32; off <<= 1){
    den += __shfl_xor(den, off, 64);
    ax  += __shfl_xor(ax,  off, 64);
    ay  += __shfl_xor(ay,  off, 64);
    az  += __shfl_xor(az,  off, 64);
    aw  += __shfl_xor(aw,  off, 64);
  }

  if (grp == 0){
    float4 s4 = ((const float4*)(sp + (size_t)node*D))[gl];
    float4 o;
    if (dg > 0){
      float inv = 1.f/den;
      o.x = fmaf(ax, inv, s4.x);
      o.y = fmaf(ay, inv, s4.y);
      o.z = fmaf(az, inv, s4.z);
      o.w = fmaf(aw, inv, s4.w);
    } else {
      o = s4;
    }
    o.x = fmaxf(o.x, 0.f); o.y = fmaxf(o.y, 0.f);
    o.z = fmaxf(o.z, 0.f); o.w = fmaxf(o.w, 0.f);
    ((float4*)(sp + (size_t)node*D))[gl] = o;
  }
}

// ---------- mean pool: register accumulation per wave strip ----------
__global__ __launch_bounds__(256) void k_pool(
    const float* __restrict__ rows, const int* __restrict__ batch,
    float* __restrict__ gsum, float* __restrict__ gcnt, int N, int rpw)
{
  const int lane = threadIdx.x & 63;
  const int wid  = threadIdx.x >> 6;
  int wi = blockIdx.x*4 + wid;
  int start = wi * rpw;
  if (start >= N) return;
  int end = min(start + rpw, N);

  float acc = 0.f, cnt = 0.f;
  int gcur = batch[start];
  #pragma unroll 4
  for (int row = start; row < end; ++row){
    int g = batch[row];                     // wave-uniform scalar load
    float val = rows[(size_t)row*D + lane]; // coalesced 256B per wave
    if (g != gcur){
      atomicAdd(gsum + (size_t)gcur*D + lane, acc);
      if (lane == 0) atomicAdd(gcnt + gcur, cnt);
      acc = 0.f; cnt = 0.f; gcur = g;
    }
    acc += val;
    cnt += 1.f;
  }
  atomicAdd(gsum + (size_t)gcur*D + lane, acc);
  if (lane == 0) atomicAdd(gcnt + gcur, cnt);
}

__global__ __launch_bounds__(256) void k_final(
    const float* __restrict__ gsum, const float* __restrict__ gcnt,
    float* __restrict__ out, int n)
{
  int i = blockIdx.x*256 + threadIdx.x;
  if (i >= n) return;
  int g = i >> 6;
  out[i] = gsum[i] / fmaxf(gcnt[g], 1.0f);
}

extern "C" void kernel_launch(void* const* d_in, const int* in_sizes, int n_in,
                              void* d_out, int out_size, void* d_ws, size_t ws_size,
                              hipStream_t stream)
{
  const float* x   = (const float*)d_in[0];
  const int*  ei   = (const int*)d_in[1];
  const int*  batch= (const int*)d_in[2];
  const float* Wq  = (const float*)d_in[3];
  const float* bq  = (const float*)d_in[4];
  const float* Wk  = (const float*)d_in[5];
  const float* bk  = (const float*)d_in[6];
  const float* Wv  = (const float*)d_in[7];
  const float* bv  = (const float*)d_in[8];
  const float* Ws  = (const float*)d_in[9];
  const float* bs  = (const float*)d_in[10];
  float* out = (float*)d_out;

  const int N = in_sizes[0] / D;   // 50000
  const int E = in_sizes[1] / 2;   // 800000
  const int* esrc = ei;
  const int* edst = ei + E;

  float* ws = (float*)d_ws;
  size_t off = 0;
  float* q    = ws + off; off += (size_t)N*D;
  float* k    = ws + off; off += (size_t)N*D;
  float* v    = ws + off; off += (size_t)N*D;
  float* sp   = ws + off; off += (size_t)N*D;   // s-proj in, relu(out) in-place
  // zero region: [deg | gsum | gcnt]
  int*   deg  = (int*)(ws + off);  off += N;
  float* gsum = ws + off; off += (size_t)NG*D;
  float* gcnt = ws + off; off += NG;
  int*   ptr  = (int*)(ws + off);  off += N;
  int*   cursor = (int*)(ws + off); off += N;
  int*   bsum = (int*)(ws + off);  off += 256;
  int*   boff = (int*)(ws + off);  off += 256;
  int*   csr_src = (int*)(ws + off); off += E;

  size_t zbytes = ((size_t)N + (size_t)NG*D + NG) * sizeof(float);
  hipMemsetAsync((void*)deg, 0, zbytes, stream);

  const int NB = (N + 255) / 256;

  k_linear4<<<1024, 256, 0, stream>>>(x, Wq,bq, Wk,bk, Wv,bv, Ws,bs, q,k,v,sp, N);
  k_hist <<<(E+255)/256, 256, 0, stream>>>(edst, deg, E);
  k_scan1<<<NB, 256, 0, stream>>>(deg, ptr, bsum, N);
  k_scan2<<<1, 256, 0, stream>>>(bsum, boff, NB);
  k_scan3<<<NB, 256, 0, stream>>>(ptr, boff, cursor, N);
  k_fill <<<(E+255)/256, 256, 0, stream>>>(esrc, edst, cursor, csr_src, E);
  k_attend<<<(N+3)/4, 256, 0, stream>>>(q, k, v, sp, ptr, deg, csr_src, N);
  const int rpw = 32;
  int nwaves = (N + rpw - 1) / rpw;
  k_pool<<<(nwaves+3)/4, 256, 0, stream>>>(sp, batch, gsum, gcnt, N, rpw);
  k_final<<<(NG*D+255)/256, 256, 0, stream>>>(gsum, gcnt, out, NG*D);
}

// Round 7
// 180.189 us; speedup vs baseline: 1.2287x; 1.2287x over previous
//
#include <hip/hip_runtime.h>
#include <hip/hip_bf16.h>

#define D 64
#define NG 64

typedef float f32x16 __attribute__((ext_vector_type(16)));

__device__ __forceinline__ float b2f(unsigned short u){
  return __uint_as_float(((unsigned)u) << 16);
}

// VALU-pipe 16-lane circular reduce step: x += row_ror<C>(x)
template<int C>
__device__ __forceinline__ float dppadd(float x){
  int t = __builtin_amdgcn_update_dpp(0, __float_as_int(x), C, 0xf, 0xf, true);
  return x + __int_as_float(t);
}

// ---------- pass 1: fused x@{Wq,Wk,Wv,Ws} + bias, + edge histogram ----------
// Wave w computes matrix w; lane l holds W-column l in 64 VGPRs; x row comes
// in via s_load_dwordx16 (wave-uniform) -> pure v_fma with SGPR multiplier.
// k and v are stored as bf16 (halves the gather bytes in k_attend).
__global__ __launch_bounds__(256) void k_linear4(
    const float* __restrict__ x,
    const float* __restrict__ Wq, const float* __restrict__ bq,
    const float* __restrict__ Wk, const float* __restrict__ bk,
    const float* __restrict__ Wv, const float* __restrict__ bv,
    const float* __restrict__ Ws, const float* __restrict__ bs,
    float* __restrict__ q, __hip_bfloat16* __restrict__ kb,
    __hip_bfloat16* __restrict__ vb, float* __restrict__ sp, int N,
    const int* __restrict__ edst, int* __restrict__ deg, int E)
{
  const int lane = threadIdx.x & 63;
  const int w    = threadIdx.x >> 6;   // wave id = matrix id

  const float* Wm = (w==0) ? Wq : (w==1) ? Wk : (w==2) ? Wv : Ws;
  const float* bm = (w==0) ? bq : (w==1) ? bk : (w==2) ? bv : bs;

  float wr[D];
  #pragma unroll
  for (int j = 0; j < D; ++j) wr[j] = Wm[j*D + lane];
  const float bias = bm[lane];

  for (int row = blockIdx.x; row < N; row += gridDim.x){
    const float* xrow = x + (size_t)row * D;
    f32x16 x0, x1, x2, x3;
    asm volatile("s_load_dwordx16 %0, %1, 0x0"  : "=s"(x0) : "s"(xrow));
    asm volatile("s_load_dwordx16 %0, %1, 0x40" : "=s"(x1) : "s"(xrow));
    asm volatile("s_load_dwordx16 %0, %1, 0x80" : "=s"(x2) : "s"(xrow));
    asm volatile("s_load_dwordx16 %0, %1, 0xc0" : "=s"(x3) : "s"(xrow));
    asm volatile("s_waitcnt lgkmcnt(0)"
                 : "+s"(x0), "+s"(x1), "+s"(x2), "+s"(x3));
    float acc = bias;
    #pragma unroll
    for (int j = 0; j < 16; ++j) acc = fmaf(x0[j], wr[j],      acc);
    #pragma unroll
    for (int j = 0; j < 16; ++j) acc = fmaf(x1[j], wr[16 + j], acc);
    #pragma unroll
    for (int j = 0; j < 16; ++j) acc = fmaf(x2[j], wr[32 + j], acc);
    #pragma unroll
    for (int j = 0; j < 16; ++j) acc = fmaf(x3[j], wr[48 + j], acc);
    size_t o = (size_t)row * D + lane;
    if (w == 0)      q[o]  = acc;
    else if (w == 1) kb[o] = __float2bfloat16(acc);
    else if (w == 2) vb[o] = __float2bfloat16(acc);
    else             sp[o] = acc;
  }

  // fused edge histogram (independent of the GEMM work above)
  for (int e = blockIdx.x*256 + threadIdx.x; e < E; e += gridDim.x*256)
    atomicAdd(deg + edst[e], 1);
}

// ---------- CSR range assignment: block scan + one atomic base per block ----
// Ranges per dst are contiguous; inter-block order is nondeterministic but the
// per-node edge multiset (what attend sums) is unchanged.
__global__ __launch_bounds__(256) void k_ptr(
    const int* __restrict__ deg, int* __restrict__ ptr, int* __restrict__ cursor,
    int* __restrict__ total, int N)
{
  __shared__ int s[256];
  __shared__ int sbase;
  int t = threadIdx.x;
  int i = blockIdx.x*256 + t;
  int val = (i < N) ? deg[i] : 0;
  s[t] = val; __syncthreads();
  #pragma unroll
  for (int off=1; off<256; off<<=1){
    int tmp = (t>=off) ? s[t-off] : 0;
    __syncthreads();
    s[t] += tmp;
    __syncthreads();
  }
  if (t == 255) sbase = atomicAdd(total, s[255]);
  __syncthreads();
  if (i < N){
    int p = sbase + s[t] - val;
    ptr[i] = p;
    cursor[i] = p;
  }
}

__global__ __launch_bounds__(256) void k_fill(
    const int* __restrict__ esrc, const int* __restrict__ edst,
    int* __restrict__ cursor, int* __restrict__ csr_src, int E)
{
  int e = blockIdx.x*256 + threadIdx.x;
  if (e >= E) return;
  int pos = atomicAdd(cursor + edst[e], 1);
  csr_src[pos] = esrc[e];
}

// ---------- fused attention gather: logits + softmax + PV + skip + ReLU ----------
// Softmax without max-subtraction (logits ~ N(0,1); clamp at 60 as guard).
// k/v are bf16 (8B per lane per row). Dot-reduce via DPP row_ror (VALU pipe,
// no LDS); the only DS op per 4 edges is the sidx broadcast shuffle.
__global__ __launch_bounds__(256) void k_attend(
    const float* __restrict__ q, const __hip_bfloat16* __restrict__ kb,
    const __hip_bfloat16* __restrict__ vb, float* __restrict__ sp,
    const int* __restrict__ ptr, const int* __restrict__ deg,
    const int* __restrict__ csr_src, int N)
{
  int node = blockIdx.x*4 + (threadIdx.x >> 6);
  if (node >= N) return;
  const int lane = threadIdx.x & 63;
  const int grp  = lane >> 4;
  const int gl   = lane & 15;

  float4 q4 = ((const float4*)(q + (size_t)node*D))[gl];
  int p0 = ptr[node], dg = deg[node];

  float den = 0.f;
  float ax=0.f, ay=0.f, az=0.f, aw=0.f;

  const unsigned short* ku = (const unsigned short*)kb;
  const unsigned short* vu = (const unsigned short*)vb;

  for (int base = 0; base < dg; base += 64){
    int nb = min(64, dg - base);
    int sidx = (lane < nb) ? csr_src[p0 + base + lane] : 0;
    int T = (nb + 3) >> 2;               // uniform trip count for all groups
    #pragma unroll 2
    for (int t = 0; t < T; ++t){
      int ei  = grp + 4*t;
      int eis = min(ei, nb - 1);         // clamped: always a valid source lane
      int s = __shfl(sidx, eis, 64);     // executed by all 64 lanes
      if (ei < nb){                      // group-uniform predicate
        ushort4 k4 = ((const ushort4*)(ku + (size_t)s*D))[gl];
        float p = q4.x*b2f(k4.x) + q4.y*b2f(k4.y)
                + q4.z*b2f(k4.z) + q4.w*b2f(k4.w);
        p = dppadd<0x121>(p);            // += row_ror:1
        p = dppadd<0x122>(p);            // += row_ror:2
        p = dppadd<0x124>(p);            // += row_ror:4
        p = dppadd<0x128>(p);            // += row_ror:8  -> 16-lane total
        float ex = __expf(fminf(p * 0.125f, 60.f));   // 1/sqrt(64)
        ushort4 v4 = ((const ushort4*)(vu + (size_t)s*D))[gl];
        den += ex;
        ax = fmaf(ex, b2f(v4.x), ax);
        ay = fmaf(ex, b2f(v4.y), ay);
        az = fmaf(ex, b2f(v4.z), az);
        aw = fmaf(ex, b2f(v4.w), aw);
      }
    }
  }

  // merge the 4 groups (lanes gl, gl+16, gl+32, gl+48): plain sums
  #pragma unroll
  for (int off = 16; off <= 32; off <<= 1){
    den += __shfl_xor(den, off, 64);
    ax  += __shfl_xor(ax,  off, 64);
    ay  += __shfl_xor(ay,  off, 64);
    az  += __shfl_xor(az,  off, 64);
    aw  += __shfl_xor(aw,  off, 64);
  }

  if (grp == 0){
    float4 s4 = ((const float4*)(sp + (size_t)node*D))[gl];
    float4 o;
    if (dg > 0){
      float inv = 1.f/den;
      o.x = fmaf(ax, inv, s4.x);
      o.y = fmaf(ay, inv, s4.y);
      o.z = fmaf(az, inv, s4.z);
      o.w = fmaf(aw, inv, s4.w);
    } else {
      o = s4;
    }
    o.x = fmaxf(o.x, 0.f); o.y = fmaxf(o.y, 0.f);
    o.z = fmaxf(o.z, 0.f); o.w = fmaxf(o.w, 0.f);
    ((float4*)(sp + (size_t)node*D))[gl] = o;
  }
}

// ---------- mean pool: register accumulation per wave strip ----------
__global__ __launch_bounds__(256) void k_pool(
    const float* __restrict__ rows, const int* __restrict__ batch,
    float* __restrict__ gsum, float* __restrict__ gcnt, int N, int rpw)
{
  const int lane = threadIdx.x & 63;
  const int wid  = threadIdx.x >> 6;
  int wi = blockIdx.x*4 + wid;
  int start = wi * rpw;
  if (start >= N) return;
  int end = min(start + rpw, N);

  float acc = 0.f, cnt = 0.f;
  int gcur = batch[start];
  #pragma unroll 4
  for (int row = start; row < end; ++row){
    int g = batch[row];                     // wave-uniform scalar load
    float val = rows[(size_t)row*D + lane]; // coalesced 256B per wave
    if (g != gcur){
      atomicAdd(gsum + (size_t)gcur*D + lane, acc);
      if (lane == 0) atomicAdd(gcnt + gcur, cnt);
      acc = 0.f; cnt = 0.f; gcur = g;
    }
    acc += val;
    cnt += 1.f;
  }
  atomicAdd(gsum + (size_t)gcur*D + lane, acc);
  if (lane == 0) atomicAdd(gcnt + gcur, cnt);
}

__global__ __launch_bounds__(256) void k_final(
    const float* __restrict__ gsum, const float* __restrict__ gcnt,
    float* __restrict__ out, int n)
{
  int i = blockIdx.x*256 + threadIdx.x;
  if (i >= n) return;
  int g = i >> 6;
  out[i] = gsum[i] / fmaxf(gcnt[g], 1.0f);
}

extern "C" void kernel_launch(void* const* d_in, const int* in_sizes, int n_in,
                              void* d_out, int out_size, void* d_ws, size_t ws_size,
                              hipStream_t stream)
{
  const float* x   = (const float*)d_in[0];
  const int*  ei   = (const int*)d_in[1];
  const int*  batch= (const int*)d_in[2];
  const float* Wq  = (const float*)d_in[3];
  const float* bq  = (const float*)d_in[4];
  const float* Wk  = (const float*)d_in[5];
  const float* bk  = (const float*)d_in[6];
  const float* Wv  = (const float*)d_in[7];
  const float* bv  = (const float*)d_in[8];
  const float* Ws  = (const float*)d_in[9];
  const float* bs  = (const float*)d_in[10];
  float* out = (float*)d_out;

  const int N = in_sizes[0] / D;   // 50000
  const int E = in_sizes[1] / 2;   // 800000
  const int* esrc = ei;
  const int* edst = ei + E;

  float* ws = (float*)d_ws;
  size_t off = 0;
  float* q    = ws + off; off += (size_t)N*D;
  __hip_bfloat16* kb = (__hip_bfloat16*)(ws + off); off += (size_t)N*D/2;
  __hip_bfloat16* vb = (__hip_bfloat16*)(ws + off); off += (size_t)N*D/2;
  float* sp   = ws + off; off += (size_t)N*D;   // s-proj in, relu(out) in-place
  // zero region: [deg | total | gsum | gcnt]
  int*   deg  = (int*)(ws + off);  off += N;
  int*   total= (int*)(ws + off);  off += 1;
  float* gsum = ws + off; off += (size_t)NG*D;
  float* gcnt = ws + off; off += NG;
  int*   ptr  = (int*)(ws + off);  off += N;
  int*   cursor = (int*)(ws + off); off += N;
  int*   csr_src = (int*)(ws + off); off += E;

  size_t zbytes = ((size_t)N + 1 + (size_t)NG*D + NG) * sizeof(float);
  hipMemsetAsync((void*)deg, 0, zbytes, stream);

  const int NB = (N + 255) / 256;

  k_linear4<<<1024, 256, 0, stream>>>(x, Wq,bq, Wk,bk, Wv,bv, Ws,bs,
                                      q, kb, vb, sp, N, edst, deg, E);
  k_ptr  <<<NB, 256, 0, stream>>>(deg, ptr, cursor, total, N);
  k_fill <<<(E+255)/256, 256, 0, stream>>>(esrc, edst, cursor, csr_src, E);
  k_attend<<<(N+3)/4, 256, 0, stream>>>(q, kb, vb, sp, ptr, deg, csr_src, N);
  const int rpw = 32;
  int nwaves = (N + rpw - 1) / rpw;
  k_pool<<<(nwaves+3)/4, 256, 0, stream>>>(sp, batch, gsum, gcnt, N, rpw);
  k_final<<<(NG*D+255)/256, 256, 0, stream>>>(gsum, gcnt, out, NG*D);
}